// Round 18
// baseline (1715.397 us; speedup 1.0000x reference)
//
#include <hip/hip_runtime.h>
#include <stdint.h>

#define TSTEPS 1024
#define S 4          // timesteps per super-iter (layer skew)
#define NK 258       // 1024/S + 2 pipeline-drain super-iters
#define L2E 1.4426950408889634f

typedef float v2f __attribute__((ext_vector_type(2)));
typedef float v4f __attribute__((ext_vector_type(4)));

__device__ __forceinline__ float rcpf_(float v) { return __builtin_amdgcn_rcpf(v); }
__device__ __forceinline__ float ex2(float v) { return __builtin_amdgcn_exp2f(v); }
#define PKFMA(a, b, c) __builtin_elementwise_fma((a), (b), (c))

// quad_perm [1,0,3,2]: exchange with lane^1 (= partner c-half) — HW-proven
__device__ __forceinline__ float dpp_x1(float v) {
    return __int_as_float(__builtin_amdgcn_update_dpp(
        0, __float_as_int(v), 0xB1, 0xF, 0xF, true));
}
// full 16-col sum: own-half v2f total + partner half (bias seeded once on c=0)
__device__ __forceinline__ float pairsum(v2f a) {
    float s = a.x + a.y;
    return s + dpp_x1(s);
}

// Opaque loads: value is asm-produced -> cannot be rematerialized as a load.
__device__ __forceinline__ v2f ldg2(const float* p) {
    v2f r; uint64_t a = (uint64_t)p;
    asm volatile("global_load_dwordx2 %0, %1, off\n\ts_waitcnt vmcnt(0)"
                 : "=v"(r) : "v"(a));
    return r;
}
__device__ __forceinline__ float ldg1(const float* p) {
    float r; uint64_t a = (uint64_t)p;
    asm volatile("global_load_dword %0, %1, off\n\ts_waitcnt vmcnt(0)"
                 : "=v"(r) : "v"(a));
    return r;
}

// 4-pair pk-FMA chain over this lane's 8 columns
#define CH4(W, H, SEED) \
    PKFMA(W[3], H[3], PKFMA(W[2], H[2], PKFMA(W[1], H[1], PKFMA(W[0], H[0], (SEED)))))

// read this lane's 8-col half of a 16-float LDS h vector (2x ds_read_b128)
#define RD2(dst, p)                                                        \
    do {                                                                   \
        v4f a0 = *(const v4f*)(p);                                         \
        v4f a1 = *(const v4f*)((p) + 4);                                   \
        dst[0] = __builtin_shufflevector(a0, a0, 0, 1);                    \
        dst[1] = __builtin_shufflevector(a0, a0, 2, 3);                    \
        dst[2] = __builtin_shufflevector(a1, a1, 0, 1);                    \
        dst[3] = __builtin_shufflevector(a1, a1, 2, 3);                    \
    } while (0)

// 3 role waves (L0,L1,L2) x 2 seqs x 32 lanes (u = unit, c = col half).
// Skewed super-steps (S=4), double-buffered partial rings, one barrier per
// super-iter (R15-proven control flow). Compute = R8-proven pair scheme:
// CH4 + pairsum reductions, pair-split sigmoid with DPP partner exchange.
// 2048 blocks -> 6144 waves -> 6 waves/SIMD: chain overlap finally deep.
__global__ __launch_bounds__(192, 6) void gru3_rs32(
    const float* __restrict__ x,      // [4096,1024,1]
    const float* __restrict__ w_ih0,  // [48,1]
    const float* __restrict__ w_ih12, // [2,48,16]
    const float* __restrict__ w_hh,   // [3,48,16]
    const float* __restrict__ b_ih,   // [3,48]
    const float* __restrict__ b_hh,   // [3,48]
    const float* __restrict__ fc_w,   // [5,16]
    const float* __restrict__ fc_b,   // [5]
    float* __restrict__ out)          // [4096,5]
{
    // [link][buf][j][s][gate*16+u]: write banks (16g+u, 48+16g+u)%32 distinct
    __shared__ float pring[2][2][S][2][48];  // 6144 B
    __shared__ float hrec[3][2][16];         // own-recurrence scratch, 384 B

    const int tid = threadIdx.x;
    const int role = tid >> 6;
    const int l63 = tid & 63;
    const int s = l63 >> 5;            // seq within block (0..1)
    const int l31 = l63 & 31;
    const int u = l31 >> 1;            // hidden unit (0..15)
    const int c = l31 & 1;             // column half; partner = lane^1
    const int c8 = c * 8;
    const int seq = blockIdx.x * 2 + s;
    const v2f zz = {0.f, 0.f};

    if (tid < 96) ((float*)hrec)[tid] = 0.f;  // h(-1) = 0 for all roles
    __syncthreads();

    if (role == 0) {
        // ---- L0 gates (w_hh[0], w_ih0) + V1-partials (w_ih12[0], L1 biases)
        v2f wr[4], wz[4], wn[4], vr[4], vz[4], vn[4];
#pragma unroll
        for (int m = 0; m < 4; ++m) {
            wr[m] = ldg2(w_hh + (u) * 16 + c8 + 2 * m) * -L2E;
            wz[m] = ldg2(w_hh + (16 + u) * 16 + c8 + 2 * m) * -L2E;
            wn[m] = ldg2(w_hh + (32 + u) * 16 + c8 + 2 * m) * (2.f * L2E);
            vr[m] = ldg2(w_ih12 + (u) * 16 + c8 + 2 * m) * -L2E;
            vz[m] = ldg2(w_ih12 + (16 + u) * 16 + c8 + 2 * m) * -L2E;
            vn[m] = ldg2(w_ih12 + (32 + u) * 16 + c8 + 2 * m) * (2.f * L2E);
        }
        const float wxr = ldg1(w_ih0 + u) * -L2E;
        const float wxz = ldg1(w_ih0 + 16 + u) * -L2E;
        const float wxn = ldg1(w_ih0 + 32 + u) * (2.f * L2E);
        const v2f sbr = {c ? 0.f : -(ldg1(b_ih + u) + ldg1(b_hh + u)) * L2E, 0.f};
        const v2f sbz = {c ? 0.f : -(ldg1(b_ih + 16 + u) + ldg1(b_hh + 16 + u)) * L2E, 0.f};
        const v2f sbn = {c ? 0.f : ldg1(b_hh + 32 + u) * (2.f * L2E), 0.f};
        const float bnx = ldg1(b_ih + 32 + u) * (2.f * L2E);
        const v2f s1r = {c ? 0.f : -(ldg1(b_ih + 48 + u) + ldg1(b_hh + 48 + u)) * L2E, 0.f};
        const v2f s1z = {c ? 0.f : -(ldg1(b_ih + 64 + u) + ldg1(b_hh + 64 + u)) * L2E, 0.f};
        const v2f s1x = {c ? 0.f : ldg1(b_ih + 80 + u) * (2.f * L2E), 0.f};

        const float* xp = x + (size_t)seq * TSTEPS;
        float* hw = &hrec[0][s][u];
        const float* hr = &hrec[0][s][c8];
        float* rw0 = &pring[0][0][0][s][0];
        float* rw1 = &pring[0][1][0][s][0];
        v2f hrep[4] = {zz, zz, zz, zz};  // h0(t-1), this lane's 8 cols
        float hown = 0.f;
        for (int K = 0; K < NK; ++K) {
            if (K < 256) {
                v4f xq = *(const v4f*)(xp + 4 * K);
                float* pb = rw0;
#pragma unroll
                for (int j = 0; j < S; ++j) {
                    float xt = xq[j];
                    v2f a;
                    a = CH4(wr, hrep, sbr);
                    float sr = fmaf(wxr, xt, pairsum(a));
                    a = CH4(wz, hrep, sbz);
                    float sz = fmaf(wxz, xt, pairsum(a));
                    a = CH4(wn, hrep, sbn);
                    float snh = pairsum(a);
                    float p = c ? sz : sr;
                    float sg = rcpf_(1.f + ex2(p));
                    float og = dpp_x1(sg);
                    float r = c ? og : sg, z = c ? sg : og;
                    float ut = fmaf(r, snh, fmaf(wxn, xt, bnx));
                    float n = fmaf(-2.f, rcpf_(ex2(ut) + 1.f), 1.f);
                    hown = fmaf(z, hown - n, n);
                    *hw = hown;        // both c lanes write same value
                    RD2(hrep, hr);     // h0(t) replicated (same-wave ordered)
                    a = CH4(vr, hrep, s1r);
                    float pr = pairsum(a);
                    a = CH4(vz, hrep, s1z);
                    float pz = pairsum(a);
                    a = CH4(vn, hrep, s1x);
                    float px = pairsum(a);
                    pb[u] = pr; pb[16 + u] = pz; pb[32 + u] = px;
                    pb += 96;
                }
            }
            __syncthreads();
            float* t_ = rw0; rw0 = rw1; rw1 = t_;
        }
    } else if (role == 1) {
        // ---- L1 gates (w_hh[1] + ring partials) + V2-partials (w_ih12[1])
        v2f wr[4], wz[4], wn[4], vr[4], vz[4], vn[4];
#pragma unroll
        for (int m = 0; m < 4; ++m) {
            wr[m] = ldg2(w_hh + (48 + u) * 16 + c8 + 2 * m) * -L2E;
            wz[m] = ldg2(w_hh + (48 + 16 + u) * 16 + c8 + 2 * m) * -L2E;
            wn[m] = ldg2(w_hh + (48 + 32 + u) * 16 + c8 + 2 * m) * (2.f * L2E);
            vr[m] = ldg2(w_ih12 + (48 + u) * 16 + c8 + 2 * m) * -L2E;
            vz[m] = ldg2(w_ih12 + (48 + 16 + u) * 16 + c8 + 2 * m) * -L2E;
            vn[m] = ldg2(w_ih12 + (48 + 32 + u) * 16 + c8 + 2 * m) * (2.f * L2E);
        }
        const v2f sbn = {c ? 0.f : ldg1(b_hh + 80 + u) * (2.f * L2E), 0.f};
        const v2f s2r = {c ? 0.f : -(ldg1(b_ih + 96 + u) + ldg1(b_hh + 96 + u)) * L2E, 0.f};
        const v2f s2z = {c ? 0.f : -(ldg1(b_ih + 112 + u) + ldg1(b_hh + 112 + u)) * L2E, 0.f};
        const v2f s2x = {c ? 0.f : ldg1(b_ih + 128 + u) * (2.f * L2E), 0.f};

        float* hw = &hrec[1][s][u];
        const float* hr = &hrec[1][s][c8];
        const float* ri0 = &pring[0][0][0][s][0];
        const float* ri1 = &pring[0][1][0][s][0];
        float* ro0 = &pring[1][0][0][s][0];
        float* ro1 = &pring[1][1][0][s][0];
        const float* rin = ri1;  // at K points to buf[(K-1)&1] (R15-proven)
        v2f hrep[4] = {zz, zz, zz, zz};
        float hown = 0.f;
        for (int K = 0; K < NK; ++K) {
            if (K >= 1 && K < 257) {
                const float* qb = rin;
                float* pb = ro0;
#pragma unroll
                for (int j = 0; j < S; ++j) {
                    float pr = qb[u], pz = qb[16 + u], px = qb[32 + u];
                    v2f a;
                    a = CH4(wr, hrep, zz);
                    float sr = pr + pairsum(a);
                    a = CH4(wz, hrep, zz);
                    float sz = pz + pairsum(a);
                    a = CH4(wn, hrep, sbn);
                    float snh = pairsum(a);
                    float p = c ? sz : sr;
                    float sg = rcpf_(1.f + ex2(p));
                    float og = dpp_x1(sg);
                    float r = c ? og : sg, z = c ? sg : og;
                    float ut = fmaf(r, snh, px);
                    float n = fmaf(-2.f, rcpf_(ex2(ut) + 1.f), 1.f);
                    hown = fmaf(z, hown - n, n);
                    *hw = hown;
                    RD2(hrep, hr);     // h1(t) replicated
                    a = CH4(vr, hrep, s2r);
                    float qr = pairsum(a);
                    a = CH4(vz, hrep, s2z);
                    float qz = pairsum(a);
                    a = CH4(vn, hrep, s2x);
                    float qx = pairsum(a);
                    pb[u] = qr; pb[16 + u] = qz; pb[32 + u] = qx;
                    pb += 96; qb += 96;
                }
            }
            __syncthreads();
            const float* t0 = (rin == ri0) ? ri1 : ri0; rin = t0;
            float* t1 = ro0; ro0 = ro1; ro1 = t1;
        }
    } else {
        // ---- L2 gates (w_hh[2] + ring partials); head at the end
        v2f wr[4], wz[4], wn[4];
#pragma unroll
        for (int m = 0; m < 4; ++m) {
            wr[m] = ldg2(w_hh + (96 + u) * 16 + c8 + 2 * m) * -L2E;
            wz[m] = ldg2(w_hh + (96 + 16 + u) * 16 + c8 + 2 * m) * -L2E;
            wn[m] = ldg2(w_hh + (96 + 32 + u) * 16 + c8 + 2 * m) * (2.f * L2E);
        }
        const v2f sbn = {c ? 0.f : ldg1(b_hh + 128 + u) * (2.f * L2E), 0.f};

        float* hw = &hrec[2][s][u];
        const float* hr = &hrec[2][s][c8];
        const float* ri0 = &pring[1][0][0][s][0];
        const float* ri1 = &pring[1][1][0][s][0];
        const float* rin = ri1;
        v2f hrep[4] = {zz, zz, zz, zz};
        float hown = 0.f;
        for (int K = 0; K < NK; ++K) {
            if (K >= 2) {
                const float* qb = rin;
#pragma unroll
                for (int j = 0; j < S; ++j) {
                    float pr = qb[u], pz = qb[16 + u], px = qb[32 + u];
                    v2f a;
                    a = CH4(wr, hrep, zz);
                    float sr = pr + pairsum(a);
                    a = CH4(wz, hrep, zz);
                    float sz = pz + pairsum(a);
                    a = CH4(wn, hrep, sbn);
                    float snh = pairsum(a);
                    float p = c ? sz : sr;
                    float sg = rcpf_(1.f + ex2(p));
                    float og = dpp_x1(sg);
                    float r = c ? og : sg, z = c ? sg : og;
                    float ut = fmaf(r, snh, px);
                    float n = fmaf(-2.f, rcpf_(ex2(ut) + 1.f), 1.f);
                    hown = fmaf(z, hown - n, n);
                    *hw = hown;
                    RD2(hrep, hr);     // h2(t) replicated
                    qb += 96;
                }
            }
            __syncthreads();
            const float* t0 = (rin == ri0) ? ri1 : ri0; rin = t0;
        }
        // ---- head on h2(1023): hrep holds this lane's 8 cols; partner half
        // via the same pairsum reduction. Lane u<5 (both c) computes out[u].
        const int ur = (u < 5) ? u : 0;
        v2f fw[4];
#pragma unroll
        for (int m = 0; m < 4; ++m) fw[m] = ldg2(fc_w + ur * 16 + c8 + 2 * m);
        const v2f fb = {c ? 0.f : ldg1(fc_b + ur), 0.f};
        v2f a = CH4(fw, hrep, fb);
        float acc = pairsum(a);
        if (u < 5 && c == 0) out[seq * 5 + u] = acc;
    }
}

extern "C" void kernel_launch(void* const* d_in, const int* in_sizes, int n_in,
                              void* d_out, int out_size, void* d_ws, size_t ws_size,
                              hipStream_t stream) {
    const float* x      = (const float*)d_in[0];
    const float* w_ih0  = (const float*)d_in[1];
    const float* w_ih12 = (const float*)d_in[2];
    const float* w_hh   = (const float*)d_in[3];
    const float* b_ih   = (const float*)d_in[4];
    const float* b_hh   = (const float*)d_in[5];
    const float* fc_w   = (const float*)d_in[6];
    const float* fc_b   = (const float*)d_in[7];
    float* out = (float*)d_out;

    // 2048 blocks x 192 threads (3 role waves, 2 seqs/block)
    // -> 6144 waves -> 6 waves/SIMD, 8 blocks/CU (LDS 6.5 KB each).
    gru3_rs32<<<2048, 192, 0, stream>>>(
        x, w_ih0, w_ih12, w_hh, b_ih, b_hh, fc_w, fc_b, out);
}

// Round 19
// 745.087 us; speedup vs baseline: 2.3023x; 2.3023x over previous
//
#include <hip/hip_runtime.h>
#include <stdint.h>

#define TSTEPS 1024
#define S 4          // timesteps per super-iter (layer skew)
#define NK 258       // 1024/S + 2 pipeline-drain super-iters
#define L2E 1.4426950408889634f

typedef float v2f __attribute__((ext_vector_type(2)));
typedef float v4f __attribute__((ext_vector_type(4)));

__device__ __forceinline__ float rcpf_(float v) { return __builtin_amdgcn_rcpf(v); }
__device__ __forceinline__ float ex2(float v) { return __builtin_amdgcn_exp2f(v); }
#define PKFMA(a, b, c) __builtin_elementwise_fma((a), (b), (c))

// quad_perm [1,0,3,2]: exchange with lane^1 (= partner c-half) — HW-proven
__device__ __forceinline__ float dpp_x1(float v) {
    return __int_as_float(__builtin_amdgcn_update_dpp(
        0, __float_as_int(v), 0xB1, 0xF, 0xF, true));
}
// full 16-col sum: own-half v2f total + partner half (bias seeded once on c=0)
__device__ __forceinline__ float pairsum(v2f a) {
    float s = a.x + a.y;
    return s + dpp_x1(s);
}

// Opaque loads: value is asm-produced -> cannot be rematerialized as a load.
__device__ __forceinline__ v2f ldg2(const float* p) {
    v2f r; uint64_t a = (uint64_t)p;
    asm volatile("global_load_dwordx2 %0, %1, off\n\ts_waitcnt vmcnt(0)"
                 : "=v"(r) : "v"(a));
    return r;
}
__device__ __forceinline__ float ldg1(const float* p) {
    float r; uint64_t a = (uint64_t)p;
    asm volatile("global_load_dword %0, %1, off\n\ts_waitcnt vmcnt(0)"
                 : "=v"(r) : "v"(a));
    return r;
}

// 4-pair pk-FMA chain over this lane's 8 columns
#define CH4(W, H, SEED) \
    PKFMA(W[3], H[3], PKFMA(W[2], H[2], PKFMA(W[1], H[1], PKFMA(W[0], H[0], (SEED)))))

// read this lane's 8-col half of a 16-float LDS h vector (2x ds_read_b128)
#define RD2(dst, p)                                                        \
    do {                                                                   \
        v4f a0 = *(const v4f*)(p);                                         \
        v4f a1 = *(const v4f*)((p) + 4);                                   \
        dst[0] = __builtin_shufflevector(a0, a0, 0, 1);                    \
        dst[1] = __builtin_shufflevector(a0, a0, 2, 3);                    \
        dst[2] = __builtin_shufflevector(a1, a1, 0, 1);                    \
        dst[3] = __builtin_shufflevector(a1, a1, 2, 3);                    \
    } while (0)

// 3 role waves (L0,L1,L2) x 2 seqs x 32 lanes (u = unit, c = col half).
// Skewed super-steps, double-buffered partial rings, one barrier per
// super-iter; compute = R8-proven pair scheme. launch_bounds min-waves = 4
// (NOT 6 — R18 showed 6 forces a 40-VGPR budget and spills the weights to
// scratch: 635 MB FETCH). VGPR ~96 -> 5 waves/SIMD residency naturally.
__global__ __launch_bounds__(192, 4) void gru3_rs32b(
    const float* __restrict__ x,      // [4096,1024,1]
    const float* __restrict__ w_ih0,  // [48,1]
    const float* __restrict__ w_ih12, // [2,48,16]
    const float* __restrict__ w_hh,   // [3,48,16]
    const float* __restrict__ b_ih,   // [3,48]
    const float* __restrict__ b_hh,   // [3,48]
    const float* __restrict__ fc_w,   // [5,16]
    const float* __restrict__ fc_b,   // [5]
    float* __restrict__ out)          // [4096,5]
{
    __shared__ float pring[2][2][S][2][48];  // 6144 B
    __shared__ float hrec[3][2][16];         // own-recurrence scratch

    const int tid = threadIdx.x;
    const int role = tid >> 6;
    const int l63 = tid & 63;
    const int s = l63 >> 5;            // seq within block (0..1)
    const int l31 = l63 & 31;
    const int u = l31 >> 1;            // hidden unit (0..15)
    const int c = l31 & 1;             // column half; partner = lane^1
    const int c8 = c * 8;
    const int seq = blockIdx.x * 2 + s;
    const v2f zz = {0.f, 0.f};

    if (tid < 96) ((float*)hrec)[tid] = 0.f;  // h(-1) = 0 for all roles
    __syncthreads();

    if (role == 0) {
        // ---- L0 gates (w_hh[0], w_ih0) + V1-partials (w_ih12[0], L1 biases)
        v2f wr[4], wz[4], wn[4], vr[4], vz[4], vn[4];
#pragma unroll
        for (int m = 0; m < 4; ++m) {
            wr[m] = ldg2(w_hh + (u) * 16 + c8 + 2 * m) * -L2E;
            wz[m] = ldg2(w_hh + (16 + u) * 16 + c8 + 2 * m) * -L2E;
            wn[m] = ldg2(w_hh + (32 + u) * 16 + c8 + 2 * m) * (2.f * L2E);
            vr[m] = ldg2(w_ih12 + (u) * 16 + c8 + 2 * m) * -L2E;
            vz[m] = ldg2(w_ih12 + (16 + u) * 16 + c8 + 2 * m) * -L2E;
            vn[m] = ldg2(w_ih12 + (32 + u) * 16 + c8 + 2 * m) * (2.f * L2E);
        }
        const float wxr = ldg1(w_ih0 + u) * -L2E;
        const float wxz = ldg1(w_ih0 + 16 + u) * -L2E;
        const float wxn = ldg1(w_ih0 + 32 + u) * (2.f * L2E);
        const v2f sbr = {c ? 0.f : -(ldg1(b_ih + u) + ldg1(b_hh + u)) * L2E, 0.f};
        const v2f sbz = {c ? 0.f : -(ldg1(b_ih + 16 + u) + ldg1(b_hh + 16 + u)) * L2E, 0.f};
        const v2f sbn = {c ? 0.f : ldg1(b_hh + 32 + u) * (2.f * L2E), 0.f};
        const float bnx = ldg1(b_ih + 32 + u) * (2.f * L2E);
        const v2f s1r = {c ? 0.f : -(ldg1(b_ih + 48 + u) + ldg1(b_hh + 48 + u)) * L2E, 0.f};
        const v2f s1z = {c ? 0.f : -(ldg1(b_ih + 64 + u) + ldg1(b_hh + 64 + u)) * L2E, 0.f};
        const v2f s1x = {c ? 0.f : ldg1(b_ih + 80 + u) * (2.f * L2E), 0.f};

        const float* xp = x + (size_t)seq * TSTEPS;
        float* hw = &hrec[0][s][u];
        const float* hr = &hrec[0][s][c8];
        float* rw0 = &pring[0][0][0][s][0];
        float* rw1 = &pring[0][1][0][s][0];
        v2f hrep[4] = {zz, zz, zz, zz};  // h0(t-1), this lane's 8 cols
        float hown = 0.f;
        for (int K = 0; K < NK; ++K) {
            if (K < 256) {
                v4f xq = *(const v4f*)(xp + 4 * K);
                float* pb = rw0;
#pragma unroll
                for (int j = 0; j < S; ++j) {
                    float xt = xq[j];
                    v2f a;
                    a = CH4(wr, hrep, sbr);
                    float sr = fmaf(wxr, xt, pairsum(a));
                    a = CH4(wz, hrep, sbz);
                    float sz = fmaf(wxz, xt, pairsum(a));
                    a = CH4(wn, hrep, sbn);
                    float snh = pairsum(a);
                    float p = c ? sz : sr;
                    float sg = rcpf_(1.f + ex2(p));
                    float og = dpp_x1(sg);
                    float r = c ? og : sg, z = c ? sg : og;
                    float ut = fmaf(r, snh, fmaf(wxn, xt, bnx));
                    float n = fmaf(-2.f, rcpf_(ex2(ut) + 1.f), 1.f);
                    hown = fmaf(z, hown - n, n);
                    *hw = hown;        // both c lanes write same value
                    RD2(hrep, hr);     // h0(t) replicated (same-wave ordered)
                    a = CH4(vr, hrep, s1r);
                    float pr = pairsum(a);
                    a = CH4(vz, hrep, s1z);
                    float pz = pairsum(a);
                    a = CH4(vn, hrep, s1x);
                    float px = pairsum(a);
                    pb[u] = pr; pb[16 + u] = pz; pb[32 + u] = px;
                    pb += 96;
                }
            }
            __syncthreads();
            float* t_ = rw0; rw0 = rw1; rw1 = t_;
        }
    } else if (role == 1) {
        // ---- L1 gates (w_hh[1] + ring partials) + V2-partials (w_ih12[1])
        v2f wr[4], wz[4], wn[4], vr[4], vz[4], vn[4];
#pragma unroll
        for (int m = 0; m < 4; ++m) {
            wr[m] = ldg2(w_hh + (48 + u) * 16 + c8 + 2 * m) * -L2E;
            wz[m] = ldg2(w_hh + (48 + 16 + u) * 16 + c8 + 2 * m) * -L2E;
            wn[m] = ldg2(w_hh + (48 + 32 + u) * 16 + c8 + 2 * m) * (2.f * L2E);
            vr[m] = ldg2(w_ih12 + (48 + u) * 16 + c8 + 2 * m) * -L2E;
            vz[m] = ldg2(w_ih12 + (48 + 16 + u) * 16 + c8 + 2 * m) * -L2E;
            vn[m] = ldg2(w_ih12 + (48 + 32 + u) * 16 + c8 + 2 * m) * (2.f * L2E);
        }
        const v2f sbn = {c ? 0.f : ldg1(b_hh + 80 + u) * (2.f * L2E), 0.f};
        const v2f s2r = {c ? 0.f : -(ldg1(b_ih + 96 + u) + ldg1(b_hh + 96 + u)) * L2E, 0.f};
        const v2f s2z = {c ? 0.f : -(ldg1(b_ih + 112 + u) + ldg1(b_hh + 112 + u)) * L2E, 0.f};
        const v2f s2x = {c ? 0.f : ldg1(b_ih + 128 + u) * (2.f * L2E), 0.f};

        float* hw = &hrec[1][s][u];
        const float* hr = &hrec[1][s][c8];
        const float* ri0 = &pring[0][0][0][s][0];
        const float* ri1 = &pring[0][1][0][s][0];
        float* ro0 = &pring[1][0][0][s][0];
        float* ro1 = &pring[1][1][0][s][0];
        const float* rin = ri1;  // at K points to buf[(K-1)&1] (R15-proven)
        v2f hrep[4] = {zz, zz, zz, zz};
        float hown = 0.f;
        for (int K = 0; K < NK; ++K) {
            if (K >= 1 && K < 257) {
                const float* qb = rin;
                float* pb = ro0;
#pragma unroll
                for (int j = 0; j < S; ++j) {
                    float pr = qb[u], pz = qb[16 + u], px = qb[32 + u];
                    v2f a;
                    a = CH4(wr, hrep, zz);
                    float sr = pr + pairsum(a);
                    a = CH4(wz, hrep, zz);
                    float sz = pz + pairsum(a);
                    a = CH4(wn, hrep, sbn);
                    float snh = pairsum(a);
                    float p = c ? sz : sr;
                    float sg = rcpf_(1.f + ex2(p));
                    float og = dpp_x1(sg);
                    float r = c ? og : sg, z = c ? sg : og;
                    float ut = fmaf(r, snh, px);
                    float n = fmaf(-2.f, rcpf_(ex2(ut) + 1.f), 1.f);
                    hown = fmaf(z, hown - n, n);
                    *hw = hown;
                    RD2(hrep, hr);     // h1(t) replicated
                    a = CH4(vr, hrep, s2r);
                    float qr = pairsum(a);
                    a = CH4(vz, hrep, s2z);
                    float qz = pairsum(a);
                    a = CH4(vn, hrep, s2x);
                    float qx = pairsum(a);
                    pb[u] = qr; pb[16 + u] = qz; pb[32 + u] = qx;
                    pb += 96; qb += 96;
                }
            }
            __syncthreads();
            const float* t0 = (rin == ri0) ? ri1 : ri0; rin = t0;
            float* t1 = ro0; ro0 = ro1; ro1 = t1;
        }
    } else {
        // ---- L2 gates (w_hh[2] + ring partials); head at the end
        v2f wr[4], wz[4], wn[4];
#pragma unroll
        for (int m = 0; m < 4; ++m) {
            wr[m] = ldg2(w_hh + (96 + u) * 16 + c8 + 2 * m) * -L2E;
            wz[m] = ldg2(w_hh + (96 + 16 + u) * 16 + c8 + 2 * m) * -L2E;
            wn[m] = ldg2(w_hh + (96 + 32 + u) * 16 + c8 + 2 * m) * (2.f * L2E);
        }
        const v2f sbn = {c ? 0.f : ldg1(b_hh + 128 + u) * (2.f * L2E), 0.f};

        float* hw = &hrec[2][s][u];
        const float* hr = &hrec[2][s][c8];
        const float* ri0 = &pring[1][0][0][s][0];
        const float* ri1 = &pring[1][1][0][s][0];
        const float* rin = ri1;
        v2f hrep[4] = {zz, zz, zz, zz};
        float hown = 0.f;
        for (int K = 0; K < NK; ++K) {
            if (K >= 2) {
                const float* qb = rin;
#pragma unroll
                for (int j = 0; j < S; ++j) {
                    float pr = qb[u], pz = qb[16 + u], px = qb[32 + u];
                    v2f a;
                    a = CH4(wr, hrep, zz);
                    float sr = pr + pairsum(a);
                    a = CH4(wz, hrep, zz);
                    float sz = pz + pairsum(a);
                    a = CH4(wn, hrep, sbn);
                    float snh = pairsum(a);
                    float p = c ? sz : sr;
                    float sg = rcpf_(1.f + ex2(p));
                    float og = dpp_x1(sg);
                    float r = c ? og : sg, z = c ? sg : og;
                    float ut = fmaf(r, snh, px);
                    float n = fmaf(-2.f, rcpf_(ex2(ut) + 1.f), 1.f);
                    hown = fmaf(z, hown - n, n);
                    *hw = hown;
                    RD2(hrep, hr);     // h2(t) replicated
                    qb += 96;
                }
            }
            __syncthreads();
            const float* t0 = (rin == ri0) ? ri1 : ri0; rin = t0;
        }
        // ---- head on h2(1023): pairsum over this lane's half + partner
        const int ur = (u < 5) ? u : 0;
        v2f fw[4];
#pragma unroll
        for (int m = 0; m < 4; ++m) fw[m] = ldg2(fc_w + ur * 16 + c8 + 2 * m);
        const v2f fb = {c ? 0.f : ldg1(fc_b + ur), 0.f};
        v2f a = CH4(fw, hrep, fb);
        float acc = pairsum(a);
        if (u < 5 && c == 0) out[seq * 5 + u] = acc;
    }
}

extern "C" void kernel_launch(void* const* d_in, const int* in_sizes, int n_in,
                              void* d_out, int out_size, void* d_ws, size_t ws_size,
                              hipStream_t stream) {
    const float* x      = (const float*)d_in[0];
    const float* w_ih0  = (const float*)d_in[1];
    const float* w_ih12 = (const float*)d_in[2];
    const float* w_hh   = (const float*)d_in[3];
    const float* b_ih   = (const float*)d_in[4];
    const float* b_hh   = (const float*)d_in[5];
    const float* fc_w   = (const float*)d_in[6];
    const float* fc_b   = (const float*)d_in[7];
    float* out = (float*)d_out;

    // 2048 blocks x 192 threads (3 role waves, 2 seqs/block)
    gru3_rs32b<<<2048, 192, 0, stream>>>(
        x, w_ih0, w_ih12, w_hh, b_ih, b_hh, fc_w, fc_b, out);
}

// Round 20
// 487.657 us; speedup vs baseline: 3.5176x; 1.5279x over previous
//
#include <hip/hip_runtime.h>
#include <stdint.h>

#define TSTEPS 1024
#define S 8          // timesteps per super-iter (layer skew); R14 had 4
#define NK 130       // 1024/S + 2 pipeline-drain super-iters
#define L2E 1.4426950408889634f
#define XPITCH 1028  // padded x row (dwords): bank-spread rows, 16B-aligned

typedef float v2f __attribute__((ext_vector_type(2)));
typedef float v4f __attribute__((ext_vector_type(4)));

__device__ __forceinline__ float rcpf_(float v) { return __builtin_amdgcn_rcpf(v); }
__device__ __forceinline__ float ex2(float v) { return __builtin_amdgcn_exp2f(v); }
#define PKFMA(a, b, c) __builtin_elementwise_fma((a), (b), (c))

// Opaque loads: value is asm-produced -> cannot be rematerialized as a load.
__device__ __forceinline__ v2f ldg2(const float* p) {
    v2f r; uint64_t a = (uint64_t)p;
    asm volatile("global_load_dwordx2 %0, %1, off\n\ts_waitcnt vmcnt(0)"
                 : "=v"(r) : "v"(a));
    return r;
}
__device__ __forceinline__ float ldg1(const float* p) {
    float r; uint64_t a = (uint64_t)p;
    asm volatile("global_load_dword %0, %1, off\n\ts_waitcnt vmcnt(0)"
                 : "=v"(r) : "v"(a));
    return r;
}

// read 16 consecutive LDS floats (one h vector) into 8 v2f (4x ds_read_b128)
#define RDH(dst, p)                                                        \
    do {                                                                   \
        v4f a0 = *(const v4f*)(p);                                         \
        v4f a1 = *(const v4f*)((p) + 4);                                   \
        v4f a2 = *(const v4f*)((p) + 8);                                   \
        v4f a3 = *(const v4f*)((p) + 12);                                  \
        dst[0] = __builtin_shufflevector(a0, a0, 0, 1);                    \
        dst[1] = __builtin_shufflevector(a0, a0, 2, 3);                    \
        dst[2] = __builtin_shufflevector(a1, a1, 0, 1);                    \
        dst[3] = __builtin_shufflevector(a1, a1, 2, 3);                    \
        dst[4] = __builtin_shufflevector(a2, a2, 0, 1);                    \
        dst[5] = __builtin_shufflevector(a2, a2, 2, 3);                    \
        dst[6] = __builtin_shufflevector(a3, a3, 0, 1);                    \
        dst[7] = __builtin_shufflevector(a3, a3, 2, 3);                    \
    } while (0)

#define DOT8(w, h, seed)                                                   \
    ({                                                                     \
        v2f _a = PKFMA(w[0], h[0], (seed));                                \
        _a = PKFMA(w[1], h[1], _a); _a = PKFMA(w[2], h[2], _a);            \
        _a = PKFMA(w[3], h[3], _a); _a = PKFMA(w[4], h[4], _a);            \
        _a = PKFMA(w[5], h[5], _a); _a = PKFMA(w[6], h[6], _a);            \
        _a = PKFMA(w[7], h[7], _a);                                        \
        _a.x + _a.y;                                                       \
    })
#define DOT16(wa, ha, wb, hb, seed)                                        \
    ({                                                                     \
        v2f _a = PKFMA(wa[0], ha[0], (seed));                              \
        _a = PKFMA(wa[1], ha[1], _a); _a = PKFMA(wa[2], ha[2], _a);        \
        _a = PKFMA(wa[3], ha[3], _a); _a = PKFMA(wa[4], ha[4], _a);        \
        _a = PKFMA(wa[5], ha[5], _a); _a = PKFMA(wa[6], ha[6], _a);        \
        _a = PKFMA(wa[7], ha[7], _a);                                      \
        _a = PKFMA(wb[0], hb[0], _a); _a = PKFMA(wb[1], hb[1], _a);        \
        _a = PKFMA(wb[2], hb[2], _a); _a = PKFMA(wb[3], hb[3], _a);        \
        _a = PKFMA(wb[4], hb[4], _a); _a = PKFMA(wb[5], hb[5], _a);        \
        _a = PKFMA(wb[6], hb[6], _a); _a = PKFMA(wb[7], hb[7], _a);        \
        _a.x + _a.y;                                                       \
    })

// Block = 3 waves (one per layer) x 4 seqs. Layers skewed by S timesteps;
// cross-layer h handoff through double-buffered rings (buf = K&1), barrier
// once per super-iter (130 total at S=8). Own-layer recurrent reads are
// same-wave DS (program-ordered) and never wait on the barrier.
__global__ __launch_bounds__(192, 3)
__attribute__((amdgpu_waves_per_eu(3, 3)))
void gru3_sk8(
    const float* __restrict__ x,      // [4096,1024,1]
    const float* __restrict__ w_ih0,  // [48,1]
    const float* __restrict__ w_ih12, // [2,48,16]
    const float* __restrict__ w_hh,   // [3,48,16]
    const float* __restrict__ b_ih,   // [3,48]
    const float* __restrict__ b_hh,   // [3,48]
    const float* __restrict__ fc_w,   // [5,16]
    const float* __restrict__ fc_b,   // [5]
    float* __restrict__ out)          // [4096,5]
{
    __shared__ float xs[4][XPITCH];          // 16448 B padded x rows
    __shared__ float hring[3][2][S][4][16];  // 12288 B [layer][buf][slot][seq][unit]
    __shared__ float h2f[4][16];             // head staging

    const int tid = threadIdx.x;
    const int role = tid >> 6;         // wave = layer
    const int lane = tid & 63;
    const int s = lane >> 4;           // seq within block (0..3)
    const int u = lane & 15;           // hidden unit
    const int seq = blockIdx.x * 4 + s;

    // ---- stage x (coalesced float4, padded rows) + zero rings
    {
        const float4* xg = (const float4*)(x + (size_t)blockIdx.x * 4 * TSTEPS);
#pragma unroll
        for (int j = 0; j < 6; ++j) {
            int idx = tid + 192 * j;
            if (idx < 1024) {
                float4 v = xg[idx];
                *(float4*)&xs[idx >> 8][(idx & 255) * 4] = v;
            }
        }
#pragma unroll
        for (int j = 0; j < 16; ++j)
            ((float*)hring)[tid + 192 * j] = 0.f;
    }
    __syncthreads();

    if (role == 0) {
        // ---- layer 0: t = K*S + j
        v2f wr[8], wz[8], wn[8];
#pragma unroll
        for (int m = 0; m < 8; ++m) {
            wr[m] = ldg2(w_hh + (u) * 16 + 2 * m) * -L2E;
            wz[m] = ldg2(w_hh + (16 + u) * 16 + 2 * m) * -L2E;
            wn[m] = ldg2(w_hh + (32 + u) * 16 + 2 * m) * (2.f * L2E);
        }
        const float wxr = ldg1(w_ih0 + u) * -L2E;
        const float wxz = ldg1(w_ih0 + 16 + u) * -L2E;
        const float wxn = ldg1(w_ih0 + 32 + u) * (2.f * L2E);
        const v2f sbr = {-(ldg1(b_ih + u) + ldg1(b_hh + u)) * L2E, 0.f};
        const v2f sbz = {-(ldg1(b_ih + 16 + u) + ldg1(b_hh + 16 + u)) * L2E, 0.f};
        const v2f sbn = {ldg1(b_hh + 32 + u) * (2.f * L2E), 0.f};
        const float bnx = ldg1(b_ih + 32 + u) * (2.f * L2E);
        float* cur = &hring[0][0][0][s][0];  // buf K&1 (slot stride 64 floats)
        float* prv = &hring[0][1][0][s][0];
        float hown = 0.f;
        for (int K = 0; K < NK; ++K) {
            if (K < 128) {
                v4f xq0 = *(const v4f*)&xs[s][K * S];
                v4f xq1 = *(const v4f*)&xs[s][K * S + 4];
#pragma unroll
                for (int j = 0; j < S; ++j) {
                    const float* rb = (j == 0) ? (prv + (S - 1) * 64)
                                               : (cur + (j - 1) * 64);
                    v2f hp[8];
                    RDH(hp, rb);
                    float xt = (j < 4) ? xq0[j] : xq1[j - 4];
                    float sr = fmaf(wxr, xt, DOT8(wr, hp, sbr));
                    float sz = fmaf(wxz, xt, DOT8(wz, hp, sbz));
                    float snh = DOT8(wn, hp, sbn);
                    float r = rcpf_(1.f + ex2(sr));
                    float z = rcpf_(1.f + ex2(sz));
                    float ut = fmaf(r, snh, fmaf(wxn, xt, bnx));
                    float n = fmaf(-2.f, rcpf_(ex2(ut) + 1.f), 1.f);
                    hown = fmaf(z, hown - n, n);
                    cur[j * 64 + u] = hown;
                }
            }
            __syncthreads();
            float* t_ = cur; cur = prv; prv = t_;
        }
    } else if (role == 1) {
        // ---- layer 1: t = (K-1)*S + j; input h0 from hring[0][(K-1)&1]
        v2f wr[8], wz[8], wn[8], vr[8], vz[8], vn[8];
#pragma unroll
        for (int m = 0; m < 8; ++m) {
            wr[m] = ldg2(w_hh + (48 + u) * 16 + 2 * m) * -L2E;
            wz[m] = ldg2(w_hh + (48 + 16 + u) * 16 + 2 * m) * -L2E;
            wn[m] = ldg2(w_hh + (48 + 32 + u) * 16 + 2 * m) * (2.f * L2E);
            vr[m] = ldg2(w_ih12 + (u) * 16 + 2 * m) * -L2E;
            vz[m] = ldg2(w_ih12 + (16 + u) * 16 + 2 * m) * -L2E;
            vn[m] = ldg2(w_ih12 + (32 + u) * 16 + 2 * m) * (2.f * L2E);
        }
        const v2f sbr = {-(ldg1(b_ih + 48 + u) + ldg1(b_hh + 48 + u)) * L2E, 0.f};
        const v2f sbz = {-(ldg1(b_ih + 64 + u) + ldg1(b_hh + 64 + u)) * L2E, 0.f};
        const v2f sbn = {ldg1(b_hh + 80 + u) * (2.f * L2E), 0.f};
        const v2f sbx = {ldg1(b_ih + 80 + u) * (2.f * L2E), 0.f};
        float* in0 = &hring[0][0][0][s][0];
        float* in1 = &hring[0][1][0][s][0];
        float* my0 = &hring[1][0][0][s][0];
        float* my1 = &hring[1][1][0][s][0];
        float* inp = in1;  // at K: in[(K-1)&1]; K=0 -> [1] (unused), swap->K=1:[0]
        float* mycur = my0; float* myprv = my1;
        float hown = 0.f;
        for (int K = 0; K < NK; ++K) {
            if (K >= 1 && K < 129) {
#pragma unroll
                for (int j = 0; j < S; ++j) {
                    const float* rin = inp + j * 64;
                    const float* rown = (j == 0) ? (myprv + (S - 1) * 64)
                                                 : (mycur + (j - 1) * 64);
                    v2f hin[8], hp[8];
                    RDH(hin, rin);
                    RDH(hp, rown);
                    float sr = DOT16(wr, hp, vr, hin, sbr);
                    float sz = DOT16(wz, hp, vz, hin, sbz);
                    float snh = DOT8(wn, hp, sbn);
                    float snx = DOT8(vn, hin, sbx);
                    float r = rcpf_(1.f + ex2(sr));
                    float z = rcpf_(1.f + ex2(sz));
                    float ut = fmaf(r, snh, snx);
                    float n = fmaf(-2.f, rcpf_(ex2(ut) + 1.f), 1.f);
                    hown = fmaf(z, hown - n, n);
                    mycur[j * 64 + u] = hown;
                }
            }
            __syncthreads();
            float* t_ = inp == in0 ? in1 : in0; inp = t_;
            t_ = mycur; mycur = myprv; myprv = t_;
        }
    } else {
        // ---- layer 2: t = (K-2)*S + j; input h1 from hring[1][(K-1)&1]
        v2f wr[8], wz[8], wn[8], vr[8], vz[8], vn[8];
#pragma unroll
        for (int m = 0; m < 8; ++m) {
            wr[m] = ldg2(w_hh + (96 + u) * 16 + 2 * m) * -L2E;
            wz[m] = ldg2(w_hh + (96 + 16 + u) * 16 + 2 * m) * -L2E;
            wn[m] = ldg2(w_hh + (96 + 32 + u) * 16 + 2 * m) * (2.f * L2E);
            vr[m] = ldg2(w_ih12 + (48 + u) * 16 + 2 * m) * -L2E;
            vz[m] = ldg2(w_ih12 + (48 + 16 + u) * 16 + 2 * m) * -L2E;
            vn[m] = ldg2(w_ih12 + (48 + 32 + u) * 16 + 2 * m) * (2.f * L2E);
        }
        const v2f sbr = {-(ldg1(b_ih + 96 + u) + ldg1(b_hh + 96 + u)) * L2E, 0.f};
        const v2f sbz = {-(ldg1(b_ih + 112 + u) + ldg1(b_hh + 112 + u)) * L2E, 0.f};
        const v2f sbn = {ldg1(b_hh + 128 + u) * (2.f * L2E), 0.f};
        const v2f sbx = {ldg1(b_ih + 128 + u) * (2.f * L2E), 0.f};
        float* in0 = &hring[1][0][0][s][0];
        float* in1 = &hring[1][1][0][s][0];
        float* my0 = &hring[2][0][0][s][0];
        float* my1 = &hring[2][1][0][s][0];
        float* inp = in1;
        float* mycur = my0; float* myprv = my1;
        float hown = 0.f;
        for (int K = 0; K < NK; ++K) {
            if (K >= 2) {
#pragma unroll
                for (int j = 0; j < S; ++j) {
                    const float* rin = inp + j * 64;
                    const float* rown = (j == 0) ? (myprv + (S - 1) * 64)
                                                 : (mycur + (j - 1) * 64);
                    v2f hin[8], hp[8];
                    RDH(hin, rin);
                    RDH(hp, rown);
                    float sr = DOT16(wr, hp, vr, hin, sbr);
                    float sz = DOT16(wz, hp, vz, hin, sbz);
                    float snh = DOT8(wn, hp, sbn);
                    float snx = DOT8(vn, hin, sbx);
                    float r = rcpf_(1.f + ex2(sr));
                    float z = rcpf_(1.f + ex2(sz));
                    float ut = fmaf(r, snh, snx);
                    float n = fmaf(-2.f, rcpf_(ex2(ut) + 1.f), 1.f);
                    hown = fmaf(z, hown - n, n);
                    mycur[j * 64 + u] = hown;
                }
            }
            __syncthreads();
            float* t_ = inp == in0 ? in1 : in0; inp = t_;
            t_ = mycur; mycur = myprv; myprv = t_;
        }
        // ---- head on h2(1023): hown holds it; same-wave LDS staging
        h2f[s][u] = hown;
        if (u < 5) {
            float acc = fc_b[u];
#pragma unroll
            for (int j = 0; j < 16; ++j)
                acc = fmaf(fc_w[u * 16 + j], h2f[s][j], acc);
            out[seq * 5 + u] = acc;
        }
    }
}

extern "C" void kernel_launch(void* const* d_in, const int* in_sizes, int n_in,
                              void* d_out, int out_size, void* d_ws, size_t ws_size,
                              hipStream_t stream) {
    const float* x      = (const float*)d_in[0];
    const float* w_ih0  = (const float*)d_in[1];
    const float* w_ih12 = (const float*)d_in[2];
    const float* w_hh   = (const float*)d_in[3];
    const float* b_ih   = (const float*)d_in[4];
    const float* b_hh   = (const float*)d_in[5];
    const float* fc_w   = (const float*)d_in[6];
    const float* fc_b   = (const float*)d_in[7];
    float* out = (float*)d_out;

    // 1024 blocks x 192 threads (3 waves: L0,L1,L2; 4 seqs/block)
    // -> 3072 waves -> 3 waves/SIMD, barrier domain = 3 waves.
    gru3_sk8<<<1024, 192, 0, stream>>>(
        x, w_ih0, w_ih12, w_hh, b_ih, b_hh, fc_w, fc_b, out);
}